// Round 1
// baseline (175.357 us; speedup 1.0000x reference)
//
#include <hip/hip_runtime.h>

// DCNv2 forward = prep (weight repack + NHWC transpose) + FUSED im2col+GEMM.
// R13: barrier-free register-direct gather. Each wave owns a disjoint
// 16px x 64cout slice; lane (quad,l16) gathers pixel l16's channels
// quad*8..+7 (2 dwordx4 per corner) -> the MFMA B-frag is born in
// registers. No Bt LDS, no per-tap __syncthreads (only 1 barrier total),
// v_cvt_pk_bf16_f32 packing. Same VMEM count as R11, ~0 LDS round-trip.
#define N_    4
#define C_    64
#define H_    128
#define W_    128
#define KW_   3
#define K_    9
#define COUT_ 64
#define HW_   (H_ * W_)     // 16384
#define NPIX  (N_ * HW_)    // 65536
#define KK_   (C_ * K_)     // 576

typedef short v8s __attribute__((ext_vector_type(8)));   // 8 bf16 (4 VGPRs)
typedef float v4f __attribute__((ext_vector_type(4)));   // MFMA C/D
typedef int   v4i __attribute__((ext_vector_type(4)));
typedef unsigned int u32;
typedef unsigned short u16;

static __device__ __forceinline__ u16 f2bf(float f) {
    union { float f; unsigned int u; } v; v.f = f;
    unsigned int r = v.u + 0x7FFFu + ((v.u >> 16) & 1u);   // RNE
    return (u16)(r >> 16);
}
// packed f32->bf16x2 (RNE), lo in [15:0]
static __device__ __forceinline__ u32 cvtpk(float lo, float hi) {
    u32 r;
    asm("v_cvt_pk_bf16_f32 %0, %1, %2" : "=v"(r) : "v"(lo), "v"(hi));
    return r;
}

// ---------------------------------------------------------------------------
// prep: one dispatch doing both prologue jobs.
//   blocks 0..1023  : NCHW->NHWC fp32 transpose xh[n][hw][c] (LDS-tiled 64x64)
//                     R13: float4 on BOTH global sides (4x fewer instrs).
//   blocks 1024..1167: wA3[o][k] = bf16(weight[o][c][tap]), k = tap*64+c
// ---------------------------------------------------------------------------
__global__ __launch_bounds__(256) void prep(
    const float* __restrict__ x, float* __restrict__ xh,
    const float* __restrict__ w, u16* __restrict__ wA3)
{
    if (blockIdx.x < 1024) {
        const int n   = blockIdx.x >> 8;            // 4 images x 256 hw-tiles
        const int hw0 = (blockIdx.x & 255) * 64;

        __shared__ float tile[64][65];              // [hw][c], pad
        const float* xb = x + n * (C_ * HW_);
        // read: lane-fast along hw (coalesced 256B/quarter), float4
#pragma unroll
        for (int i = 0; i < 4; ++i) {
            const int idx = i * 256 + threadIdx.x;  // 0..1023
            const int q   = idx & 15;               // hw quad 0..15
            const int c   = idx >> 4;               // 0..63
            const v4f v = *(const v4f*)&xb[c * HW_ + hw0 + 4 * q];
            tile[4 * q + 0][c] = v.x;
            tile[4 * q + 1][c] = v.y;
            tile[4 * q + 2][c] = v.z;
            tile[4 * q + 3][c] = v.w;
        }
        __syncthreads();
        float* xo = xh + ((size_t)n * HW_ + hw0) * 64;
        // write: lane-fast along c (coalesced 256B/quarter), float4
#pragma unroll
        for (int i = 0; i < 4; ++i) {
            const int idx = i * 256 + threadIdx.x;
            const int c4  = idx & 15;               // c quad 0..15
            const int hr  = idx >> 4;               // 0..63
            v4f v;
            v.x = tile[hr][4 * c4 + 0];
            v.y = tile[hr][4 * c4 + 1];
            v.z = tile[hr][4 * c4 + 2];
            v.w = tile[hr][4 * c4 + 3];
            *(v4f*)&xo[hr * 64 + 4 * c4] = v;
        }
    } else {
        const int tid = (blockIdx.x - 1024) * 256 + threadIdx.x;  // 0..36863
        if (tid < COUT_ * KK_) {
            const int k   = tid % KK_;              // tap*64 + c
            const int o   = tid / KK_;
            const int c   = k & 63;
            const int tap = k >> 6;
            wA3[tid] = f2bf(w[o * (C_ * K_) + c * K_ + tap]);
        }
    }
}

// ---------------------------------------------------------------------------
// Fused im2col+GEMM. Block = 256 thr / 4 waves, covers 64 px x 64 cout.
// Wave wv owns px slice wv*16..wv*16+15 x ALL 64 cout (disjoint px -> no
// redundant gather). Phase 1 (one barrier): 576 (px,tap) coef sets -> LDS.
// Main loop over 9 taps, NO barriers:
//   lane (quad,l16): gather pixel l16, channels {kc*32+quad*8..+7} for both
//   kc via 4 corner base addrs x 4 dwordx4 at imm offsets {0,16,128,144}B.
//   16 fp32x4 bilinear fmas -> 8 cvt_pk_bf16 -> B-frags in registers ->
//   8 MFMA 16x16x32 (A from wA3, L1-hot). Compiler pipelines taps freely.
// ---------------------------------------------------------------------------
__global__ __launch_bounds__(256, 2) void dcn_fused(
    const float* __restrict__ xh,      // (N, HW, C) fp32
    const float* __restrict__ offset,  // (N, 2*K, H, W)
    const float* __restrict__ mask,    // (N, K, H, W)
    const u16* __restrict__ wA3,       // (COUT, KK) bf16, k = tap*64+c
    const float* __restrict__ bias,
    float* __restrict__ out)           // (N, Cout, H, W)
{
    const int tid  = threadIdx.x;
    const int lane = tid & 63;
    const int wv   = tid >> 6;
    const int quad = lane >> 4;
    const int l16  = lane & 15;

    const int lb  = (blockIdx.x & 7) * 128 + (blockIdx.x >> 3);  // XCD swizzle
    const int pxb = lb * 64;                     // 64 | HW_: one image per block
    const int n   = pxb >> 14;
    const int hwb = pxb & (HW_ - 1);

    __shared__ float cw[576][4];                 // 9.2 KB bilinear weights
    __shared__ int   ci[576][4];                 // 9.2 KB corner indices

    // ---- phase 1: all coefs for this block's 64 px x 9 taps ----
#pragma unroll
    for (int r = 0; r < 3; ++r) {
        const int e = tid + 256 * r;
        if (e < 576) {
            const int p  = e / 9;                // magic-mul
            const int t  = e - p * 9;
            const int hw = hwb + p;
            const int ho = hw >> 7;
            const int wo = hw & (W_ - 1);
            const int ky = t / KW_;
            const int kx = t - ky * KW_;

            const float offy = offset[n * (2 * K_ * HW_) + (2 * t + 0) * HW_ + hw];
            const float offx = offset[n * (2 * K_ * HW_) + (2 * t + 1) * HW_ + hw];
            const float mval = mask[n * (K_ * HW_) + t * HW_ + hw];

            const float py = (float)(ho - 1 + ky) + offy;   // stride=1,pad=1,dil=1
            const float qx = (float)(wo - 1 + kx) + offx;
            const float y0f = floorf(py), x0f = floorf(qx);
            const float ly = py - y0f, lx = qx - x0f;
            const int y0 = (int)y0f, x0 = (int)x0f;
            const int y1 = y0 + 1,   x1 = x0 + 1;
            const bool vy0 = (y0 >= 0) & (y0 < H_);
            const bool vy1 = (y1 >= 0) & (y1 < H_);
            const bool vx0 = (x0 >= 0) & (x0 < W_);
            const bool vx1 = (x1 >= 0) & (x1 < W_);
            const int cy0 = min(max(y0, 0), H_ - 1);
            const int cy1 = min(max(y1, 0), H_ - 1);
            const int cx0 = min(max(x0, 0), W_ - 1);
            const int cx1 = min(max(x1, 0), W_ - 1);

            float* q = &cw[e][0];
            q[0] = (1.f - ly) * (1.f - lx) * mval * ((vy0 && vx0) ? 1.f : 0.f);
            q[1] = (1.f - ly) * lx         * mval * ((vy0 && vx1) ? 1.f : 0.f);
            q[2] = ly         * (1.f - lx) * mval * ((vy1 && vx0) ? 1.f : 0.f);
            q[3] = ly         * lx         * mval * ((vy1 && vx1) ? 1.f : 0.f);
            int* qi = &ci[e][0];
            qi[0] = cy0 * W_ + cx0;
            qi[1] = cy0 * W_ + cx1;
            qi[2] = cy1 * W_ + cx0;
            qi[3] = cy1 * W_ + cx1;
        }
    }
    __syncthreads();                             // the ONLY barrier

    const int pxw = wv * 16;                     // wave's local pixel base
    const int pxl = pxw + l16;                   // this lane's local pixel
    // lane's channel base: quad*8 (kc adds +32 floats via imm offset)
    const float* xb = xh + ((size_t)n * HW_) * 64 + quad * 8;

    v4f acc[4];                                  // mh=0..3: cout mh*16+l16
#pragma unroll
    for (int mh = 0; mh < 4; ++mh) acc[mh] = (v4f){0.f, 0.f, 0.f, 0.f};

#pragma unroll
    for (int t = 0; t < K_; ++t) {
        const v4f f = *(const v4f*)&cw[pxl * 9 + t][0];
        const v4i o = *(const v4i*)&ci[pxl * 9 + t][0];
        const float* p0 = xb + (size_t)o.x * 64;
        const float* p1 = xb + (size_t)o.y * 64;
        const float* p2 = xb + (size_t)o.z * 64;
        const float* p3 = xb + (size_t)o.w * 64;
        // [h]: h=0 -> ch quad*8+0..3 (kc0), h=1 -> +4..7 (kc0),
        //      h=2 -> kc1 +0..3,           h=3 -> kc1 +4..7
        v4f c0[4], c1[4], c2[4], c3[4];
        c0[0] = *(const v4f*)(p0);      c0[1] = *(const v4f*)(p0 + 4);
        c0[2] = *(const v4f*)(p0 + 32); c0[3] = *(const v4f*)(p0 + 36);
        c1[0] = *(const v4f*)(p1);      c1[1] = *(const v4f*)(p1 + 4);
        c1[2] = *(const v4f*)(p1 + 32); c1[3] = *(const v4f*)(p1 + 36);
        c2[0] = *(const v4f*)(p2);      c2[1] = *(const v4f*)(p2 + 4);
        c2[2] = *(const v4f*)(p2 + 32); c2[3] = *(const v4f*)(p2 + 36);
        c3[0] = *(const v4f*)(p3);      c3[1] = *(const v4f*)(p3 + 4);
        c3[2] = *(const v4f*)(p3 + 32); c3[3] = *(const v4f*)(p3 + 36);

        float rr[16];
#pragma unroll
        for (int h = 0; h < 4; ++h)
#pragma unroll
            for (int j = 0; j < 4; ++j)
                rr[h * 4 + j] = fmaf(f.x, c0[h][j], fmaf(f.y, c1[h][j],
                                fmaf(f.z, c2[h][j], f.w * c3[h][j])));

        union { v8s v[2]; u32 w[8]; } B;         // B.v[kc] = B-frag, kc chunk
#pragma unroll
        for (int i = 0; i < 8; ++i)
            B.w[i] = cvtpk(rr[2 * i], rr[2 * i + 1]);

#pragma unroll
        for (int kc = 0; kc < 2; ++kc) {
            const u16* ap = wA3 + (size_t)l16 * KK_ + t * 64 + kc * 32 + quad * 8;
#pragma unroll
            for (int mh = 0; mh < 4; ++mh) {
                const v8s afr = *(const v8s*)(ap + (size_t)mh * 16 * KK_);
                acc[mh] = __builtin_amdgcn_mfma_f32_16x16x32_bf16(
                    afr, B.v[kc], acc[mh], 0, 0, 0);
            }
        }
    }

    // D layout (R4-verified): col = l16 (px), row = quad*4 + r (cout mod 16)
    float* outb = out + n * (COUT_ * HW_) + hwb + pxw + l16;
#pragma unroll
    for (int mh = 0; mh < 4; ++mh)
#pragma unroll
        for (int r = 0; r < 4; ++r) {
            const int m = mh * 16 + quad * 4 + r;
            outb[m * HW_] = acc[mh][r] + bias[m];
        }
}

// ---------------------------------------------------------------------------
// Fallback (ws too small): R3-style direct fp32 kernel, no ws needed.
// ---------------------------------------------------------------------------
__global__ __launch_bounds__(256) void dcn_fallback(
    const float* __restrict__ x, const float* __restrict__ offset,
    const float* __restrict__ mask, const float* __restrict__ wptr,
    const float* __restrict__ bias, float* __restrict__ out)
{
    const int pix = blockIdx.x * 256 + threadIdx.x;
    const int n = pix >> 14, hw = pix & (HW_ - 1);
    const int ho = hw >> 7,  wo = hw & (W_ - 1);
    float acc[COUT_];
#pragma unroll
    for (int o = 0; o < COUT_; ++o) acc[o] = bias[o];
    const float* xn   = x + n * (C_ * HW_);
    const float* offn = offset + n * (2 * K_ * HW_) + hw;
    const float* mn   = mask + n * (K_ * HW_) + hw;
    for (int ct = 0; ct < C_; ct += 8) {
        for (int k = 0; k < K_; ++k) {
            const int ky = k / KW_, kx = k - ky * KW_;
            const float off_y = offn[(2 * k + 0) * HW_];
            const float off_x = offn[(2 * k + 1) * HW_];
            const float m = mn[k * HW_];
            const float py = (float)(ho - 1 + ky) + off_y;
            const float px = (float)(wo - 1 + kx) + off_x;
            const float y0f = floorf(py), x0f = floorf(px);
            const float ly = py - y0f, lx = px - x0f;
            const int y0 = (int)y0f, x0 = (int)x0f, y1 = y0 + 1, x1 = x0 + 1;
            const bool vy0 = (y0 >= 0) & (y0 < H_), vy1 = (y1 >= 0) & (y1 < H_);
            const bool vx0 = (x0 >= 0) & (x0 < W_), vx1 = (x1 >= 0) & (x1 < W_);
            const int cy0 = min(max(y0, 0), H_ - 1), cy1 = min(max(y1, 0), H_ - 1);
            const int cx0 = min(max(x0, 0), W_ - 1), cx1 = min(max(x1, 0), W_ - 1);
            const int i00 = cy0 * W_ + cx0, i01 = cy0 * W_ + cx1;
            const int i10 = cy1 * W_ + cx0, i11 = cy1 * W_ + cx1;
            const float f00 = (1.f - ly) * (1.f - lx) * m * ((vy0 && vx0) ? 1.f : 0.f);
            const float f01 = (1.f - ly) * lx * m * ((vy0 && vx1) ? 1.f : 0.f);
            const float f10 = ly * (1.f - lx) * m * ((vy1 && vx0) ? 1.f : 0.f);
            const float f11 = ly * lx * m * ((vy1 && vx1) ? 1.f : 0.f);
            for (int cc = 0; cc < 8; ++cc) {
                const int c = ct + cc;
                const float* xc = xn + c * HW_;
                const float val = fmaf(f00, xc[i00], fmaf(f01, xc[i01],
                                  fmaf(f10, xc[i10], f11 * xc[i11])));
#pragma unroll
                for (int o = 0; o < COUT_; ++o)
                    acc[o] = fmaf(wptr[o * (C_ * K_) + c * K_ + k], val, acc[o]);
            }
        }
    }
    float* outp = out + n * (COUT_ * HW_) + hw;
#pragma unroll
    for (int o = 0; o < COUT_; ++o) outp[o * HW_] = acc[o];
}

extern "C" void kernel_launch(void* const* d_in, const int* in_sizes, int n_in,
                              void* d_out, int out_size, void* d_ws, size_t ws_size,
                              hipStream_t stream) {
    const float* x      = (const float*)d_in[0];
    const float* offset = (const float*)d_in[1];
    const float* mask   = (const float*)d_in[2];
    const float* weight = (const float*)d_in[3];
    const float* bias   = (const float*)d_in[4];
    float* out = (float*)d_out;

    const size_t xh_bytes = (size_t)NPIX * C_ * sizeof(float);     // 16.8 MB
    const size_t wA_bytes = (size_t)COUT_ * KK_ * sizeof(u16);     // 73.7 KB

    if (ws_size >= xh_bytes + wA_bytes) {
        float* xh  = (float*)d_ws;
        u16*   wA3 = (u16*)((char*)d_ws + xh_bytes);
        prep<<<1024 + 144, 256, 0, stream>>>(x, xh, weight, wA3);
        dcn_fused<<<NPIX / 64, 256, 0, stream>>>(xh, offset, mask, wA3, bias, out);
    } else {
        dcn_fallback<<<NPIX / 256, 256, 0, stream>>>(x, offset, mask, weight, bias, out);
    }
}

// Round 2
// 119.670 us; speedup vs baseline: 1.4653x; 1.4653x over previous
//
#include <hip/hip_runtime.h>

// DCNv2 forward = prep (weight repack + NHWC transpose) + FUSED im2col+GEMM.
// R14: R11 structure (quarter-wave gather, LDS-staged B, 1 barrier/tap) with
// an EXPLICIT 2-tap software pipeline: ISSUE(t+2) loads into named register
// stages (LA/LB), MFMA(t) from Bt[t&1], FINISH(t+1) = fma+pack+ds_write into
// Bt[t&1^1]. Loads get ~1.5 iterations of slack before consumption -> the
// scattered-load latency R11 paid exposed per tap is hidden. R13 proved the
// compiler will NOT do this on its own (VGPR=44, serial chain, 2x slower).
#define N_    4
#define C_    64
#define H_    128
#define W_    128
#define KW_   3
#define K_    9
#define COUT_ 64
#define HW_   (H_ * W_)     // 16384
#define NPIX  (N_ * HW_)    // 65536
#define KK_   (C_ * K_)     // 576

typedef short v8s __attribute__((ext_vector_type(8)));   // 8 bf16 (4 VGPRs)
typedef float v4f __attribute__((ext_vector_type(4)));   // MFMA C/D
typedef int   v4i __attribute__((ext_vector_type(4)));
typedef unsigned int u32;
typedef unsigned short u16;
typedef unsigned int v2u __attribute__((ext_vector_type(2)));

static __device__ __forceinline__ u16 f2bf(float f) {
    union { float f; unsigned int u; } v; v.f = f;
    unsigned int r = v.u + 0x7FFFu + ((v.u >> 16) & 1u);   // RNE
    return (u16)(r >> 16);
}
// packed f32->bf16x2 (RNE), lo in [15:0]
static __device__ __forceinline__ u32 cvtpk(float lo, float hi) {
    u32 r;
    asm("v_cvt_pk_bf16_f32 %0, %1, %2" : "=v"(r) : "v"(lo), "v"(hi));
    return r;
}

// ---------------------------------------------------------------------------
// prep: one dispatch doing both prologue jobs.
//   blocks 0..1023  : NCHW->NHWC fp32 transpose xh[n][hw][c], float4 both sides
//   blocks 1024..1167: wA3[o][k] = bf16(weight[o][c][tap]), k = tap*64+c
// ---------------------------------------------------------------------------
__global__ __launch_bounds__(256) void prep(
    const float* __restrict__ x, float* __restrict__ xh,
    const float* __restrict__ w, u16* __restrict__ wA3)
{
    if (blockIdx.x < 1024) {
        const int n   = blockIdx.x >> 8;            // 4 images x 256 hw-tiles
        const int hw0 = (blockIdx.x & 255) * 64;

        __shared__ float tile[64][65];              // [hw][c], pad
        const float* xb = x + n * (C_ * HW_);
#pragma unroll
        for (int i = 0; i < 4; ++i) {
            const int idx = i * 256 + threadIdx.x;  // 0..1023
            const int q   = idx & 15;               // hw quad 0..15
            const int c   = idx >> 4;               // 0..63
            const v4f v = *(const v4f*)&xb[c * HW_ + hw0 + 4 * q];
            tile[4 * q + 0][c] = v.x;
            tile[4 * q + 1][c] = v.y;
            tile[4 * q + 2][c] = v.z;
            tile[4 * q + 3][c] = v.w;
        }
        __syncthreads();
        float* xo = xh + ((size_t)n * HW_ + hw0) * 64;
#pragma unroll
        for (int i = 0; i < 4; ++i) {
            const int idx = i * 256 + threadIdx.x;
            const int c4  = idx & 15;               // c quad 0..15
            const int hr  = idx >> 4;               // 0..63
            v4f v;
            v.x = tile[hr][4 * c4 + 0];
            v.y = tile[hr][4 * c4 + 1];
            v.z = tile[hr][4 * c4 + 2];
            v.w = tile[hr][4 * c4 + 3];
            *(v4f*)&xo[hr * 64 + 4 * c4] = v;
        }
    } else {
        const int tid = (blockIdx.x - 1024) * 256 + threadIdx.x;  // 0..36863
        if (tid < COUT_ * KK_) {
            const int k   = tid % KK_;              // tap*64 + c
            const int o   = tid / KK_;
            const int c   = k & 63;
            const int tap = k >> 6;
            wA3[tid] = f2bf(w[o * (C_ * K_) + c * K_ + tap]);
        }
    }
}

// ---------------------------------------------------------------------------
// Fused im2col+GEMM. Block = 256 thr / 4 waves, 64 px x 64 cout.
// Gather identity (R11): quarter-wave per pixel — lane (qtr,c4) loads float4
// (4 channels) per corner; per instruction the wave covers 4 pixels x 256B
// contiguous (well coalesced). Wave wv gathers px wv*16..+15.
// Pipeline (R14): 2 named register stages LA/LB of 16 v4f each.
//   iter t: ISSUE(t+2) -> stage; 8x MFMA(t) from Bt[t&1];
//           FINISH(t+1): vmcnt-wait prior stage, fma+pack, ds_write
//           Bt[t&1^1]; ONE barrier.
// ---------------------------------------------------------------------------
__global__ __launch_bounds__(256, 2) void dcn_fused(
    const float* __restrict__ xh,      // (N, HW, C) fp32
    const float* __restrict__ offset,  // (N, 2*K, H, W)
    const float* __restrict__ mask,    // (N, K, H, W)
    const u16* __restrict__ wA3,       // (COUT, KK) bf16, k = tap*64+c
    const float* __restrict__ bias,
    float* __restrict__ out)           // (N, Cout, H, W)
{
    const int tid  = threadIdx.x;
    const int lane = tid & 63;
    const int wv   = tid >> 6;
    const int quad = lane >> 4;        // MFMA: k-subgroup / gather: pixel-in-4
    const int l16  = lane & 15;        // MFMA: row-col lane / gather: channel quad

    const int lb  = (blockIdx.x & 7) * 128 + (blockIdx.x >> 3);  // XCD swizzle
    const int pxb = lb * 64;                     // 64 | HW_: one image per block
    const int n   = pxb >> 14;
    const int hwb = pxb & (HW_ - 1);

    __shared__ float cw[576][4];                 // 9.2 KB bilinear weights
    __shared__ int   ci[576][4];                 // 9.2 KB corner indices
    __shared__ u16   Bt[2][64][72];              // 18.4 KB [buf][px][c pad 72]

    // ---- phase 1: all coefs for this block's 64 px x 9 taps ----
#pragma unroll
    for (int r = 0; r < 3; ++r) {
        const int e = tid + 256 * r;
        if (e < 576) {
            const int p  = e / 9;                // magic-mul
            const int t  = e - p * 9;
            const int hw = hwb + p;
            const int ho = hw >> 7;
            const int wo = hw & (W_ - 1);
            const int ky = t / KW_;
            const int kx = t - ky * KW_;

            const float offy = offset[n * (2 * K_ * HW_) + (2 * t + 0) * HW_ + hw];
            const float offx = offset[n * (2 * K_ * HW_) + (2 * t + 1) * HW_ + hw];
            const float mval = mask[n * (K_ * HW_) + t * HW_ + hw];

            const float py = (float)(ho - 1 + ky) + offy;   // stride=1,pad=1,dil=1
            const float qx = (float)(wo - 1 + kx) + offx;
            const float y0f = floorf(py), x0f = floorf(qx);
            const float ly = py - y0f, lx = qx - x0f;
            const int y0 = (int)y0f, x0 = (int)x0f;
            const int y1 = y0 + 1,   x1 = x0 + 1;
            const bool vy0 = (y0 >= 0) & (y0 < H_);
            const bool vy1 = (y1 >= 0) & (y1 < H_);
            const bool vx0 = (x0 >= 0) & (x0 < W_);
            const bool vx1 = (x1 >= 0) & (x1 < W_);
            const int cy0 = min(max(y0, 0), H_ - 1);
            const int cy1 = min(max(y1, 0), H_ - 1);
            const int cx0 = min(max(x0, 0), W_ - 1);
            const int cx1 = min(max(x1, 0), W_ - 1);

            float* q = &cw[e][0];
            q[0] = (1.f - ly) * (1.f - lx) * mval * ((vy0 && vx0) ? 1.f : 0.f);
            q[1] = (1.f - ly) * lx         * mval * ((vy0 && vx1) ? 1.f : 0.f);
            q[2] = ly         * (1.f - lx) * mval * ((vy1 && vx0) ? 1.f : 0.f);
            q[3] = ly         * lx         * mval * ((vy1 && vx1) ? 1.f : 0.f);
            int* qi = &ci[e][0];
            qi[0] = cy0 * W_ + cx0;
            qi[1] = cy0 * W_ + cx1;
            qi[2] = cy1 * W_ + cx0;
            qi[3] = cy1 * W_ + cx1;
        }
    }
    __syncthreads();

    // gather identity: quarter-wave per pixel, 4 channels per lane
    const float* xb4 = xh + ((size_t)n * HW_) * 64 + 4 * l16;

    // wave's MFMA identity: cout half x pixel half
    const int mb   = (wv & 1) * 32;
    const int pxwl = (wv >> 1) * 32;             // local pixel base for MFMA

    v4f acc[2][2];
#pragma unroll
    for (int mh = 0; mh < 2; ++mh)
#pragma unroll
        for (int nh = 0; nh < 2; ++nh)
            acc[mh][nh] = (v4f){0.f, 0.f, 0.f, 0.f};

    // register stages: 16 v4f each (4 pixels x 4 corners)
    v4f LA[4][4], LB[4][4];

    // issue tap t's 16 corner loads into stage R
#define ISSUE(t, R)                                                         \
    {                                                                       \
        _Pragma("unroll")                                                   \
        for (int i = 0; i < 4; ++i) {                                       \
            const int p = wv * 16 + 4 * i + quad;                           \
            const v4i o = *(const v4i*)&ci[p * 9 + (t)][0];                 \
            R[i][0] = *(const v4f*)(xb4 + (size_t)o.x * 64);                \
            R[i][1] = *(const v4f*)(xb4 + (size_t)o.y * 64);                \
            R[i][2] = *(const v4f*)(xb4 + (size_t)o.z * 64);                \
            R[i][3] = *(const v4f*)(xb4 + (size_t)o.w * 64);                \
        }                                                                   \
    }

    // consume stage R for tap t: bilinear fma + bf16 pack + LDS write
#define FINISH(t, R, b)                                                     \
    {                                                                       \
        _Pragma("unroll")                                                   \
        for (int i = 0; i < 4; ++i) {                                       \
            const int p = wv * 16 + 4 * i + quad;                           \
            const v4f f = *(const v4f*)&cw[p * 9 + (t)][0];                 \
            float r0 = fmaf(f.x, R[i][0].x, fmaf(f.y, R[i][1].x,            \
                       fmaf(f.z, R[i][2].x, f.w * R[i][3].x)));             \
            float r1 = fmaf(f.x, R[i][0].y, fmaf(f.y, R[i][1].y,            \
                       fmaf(f.z, R[i][2].y, f.w * R[i][3].y)));             \
            float r2 = fmaf(f.x, R[i][0].z, fmaf(f.y, R[i][1].z,            \
                       fmaf(f.z, R[i][2].z, f.w * R[i][3].z)));             \
            float r3 = fmaf(f.x, R[i][0].w, fmaf(f.y, R[i][1].w,            \
                       fmaf(f.z, R[i][2].w, f.w * R[i][3].w)));             \
            v2u pk;                                                         \
            pk.x = cvtpk(r0, r1);                                           \
            pk.y = cvtpk(r2, r3);                                           \
            *(v2u*)&Bt[b][p][4 * l16] = pk;                                 \
        }                                                                   \
    }

    // ---- prologue: fill the 2-deep pipeline ----
    ISSUE(0, LA)
    ISSUE(1, LB)
    FINISH(0, LA, 0)
    __syncthreads();

    // ---- main loop: 9 taps, 1 barrier each, loads 2 taps ahead ----
#pragma unroll
    for (int t = 0; t < K_; ++t) {
        const int buf = t & 1;
        if ((t & 1) == 0) {
            if (t + 2 < K_) ISSUE(t + 2, LA)
        } else {
            if (t + 2 < K_) ISSUE(t + 2, LB)
        }

        // MFMA(t): A-frags from wA3 (k = t*64 + kc*32 + quad*8), B from Bt[buf]
#pragma unroll
        for (int kc = 0; kc < 2; ++kc) {
            v8s bfr[2];
#pragma unroll
            for (int nh = 0; nh < 2; ++nh)
                bfr[nh] = *(const v8s*)&Bt[buf][pxwl + nh * 16 + l16][kc * 32 + quad * 8];
            v8s afr[2];
#pragma unroll
            for (int mh = 0; mh < 2; ++mh)
                afr[mh] = *(const v8s*)(wA3 + (size_t)(mb + mh * 16 + l16) * KK_
                                            + t * 64 + kc * 32 + quad * 8);
#pragma unroll
            for (int mh = 0; mh < 2; ++mh)
#pragma unroll
                for (int nh = 0; nh < 2; ++nh)
                    acc[mh][nh] = __builtin_amdgcn_mfma_f32_16x16x32_bf16(
                        afr[mh], bfr[nh], acc[mh][nh], 0, 0, 0);
        }

        if ((t & 1) == 0) {
            if (t + 1 < K_) FINISH(t + 1, LB, buf ^ 1)
        } else {
            if (t + 1 < K_) FINISH(t + 1, LA, buf ^ 1)
        }
        __syncthreads();   // MFMA(t) reads done AND FINISH(t+1) writes done
    }
#undef ISSUE
#undef FINISH

    // D layout (R4-verified): col = l16 (px), row = quad*4 + r (cout)
    float* outb = out + n * (COUT_ * HW_);
#pragma unroll
    for (int mh = 0; mh < 2; ++mh)
#pragma unroll
        for (int nh = 0; nh < 2; ++nh)
#pragma unroll
            for (int r = 0; r < 4; ++r) {
                const int m = mb + mh * 16 + quad * 4 + r;
                outb[m * HW_ + hwb + pxwl + nh * 16 + l16] = acc[mh][nh][r] + bias[m];
            }
}

// ---------------------------------------------------------------------------
// Fallback (ws too small): R3-style direct fp32 kernel, no ws needed.
// ---------------------------------------------------------------------------
__global__ __launch_bounds__(256) void dcn_fallback(
    const float* __restrict__ x, const float* __restrict__ offset,
    const float* __restrict__ mask, const float* __restrict__ wptr,
    const float* __restrict__ bias, float* __restrict__ out)
{
    const int pix = blockIdx.x * 256 + threadIdx.x;
    const int n = pix >> 14, hw = pix & (HW_ - 1);
    const int ho = hw >> 7,  wo = hw & (W_ - 1);
    float acc[COUT_];
#pragma unroll
    for (int o = 0; o < COUT_; ++o) acc[o] = bias[o];
    const float* xn   = x + n * (C_ * HW_);
    const float* offn = offset + n * (2 * K_ * HW_) + hw;
    const float* mn   = mask + n * (K_ * HW_) + hw;
    for (int ct = 0; ct < C_; ct += 8) {
        for (int k = 0; k < K_; ++k) {
            const int ky = k / KW_, kx = k - ky * KW_;
            const float off_y = offn[(2 * k + 0) * HW_];
            const float off_x = offn[(2 * k + 1) * HW_];
            const float m = mn[k * HW_];
            const float py = (float)(ho - 1 + ky) + off_y;
            const float px = (float)(wo - 1 + kx) + off_x;
            const float y0f = floorf(py), x0f = floorf(px);
            const float ly = py - y0f, lx = px - x0f;
            const int y0 = (int)y0f, x0 = (int)x0f, y1 = y0 + 1, x1 = x0 + 1;
            const bool vy0 = (y0 >= 0) & (y0 < H_), vy1 = (y1 >= 0) & (y1 < H_);
            const bool vx0 = (x0 >= 0) & (x0 < W_), vx1 = (x1 >= 0) & (x1 < W_);
            const int cy0 = min(max(y0, 0), H_ - 1), cy1 = min(max(y1, 0), H_ - 1);
            const int cx0 = min(max(x0, 0), W_ - 1), cx1 = min(max(x1, 0), W_ - 1);
            const int i00 = cy0 * W_ + cx0, i01 = cy0 * W_ + cx1;
            const int i10 = cy1 * W_ + cx0, i11 = cy1 * W_ + cx1;
            const float f00 = (1.f - ly) * (1.f - lx) * m * ((vy0 && vx0) ? 1.f : 0.f);
            const float f01 = (1.f - ly) * lx * m * ((vy0 && vx1) ? 1.f : 0.f);
            const float f10 = ly * (1.f - lx) * m * ((vy1 && vx0) ? 1.f : 0.f);
            const float f11 = ly * lx * m * ((vy1 && vx1) ? 1.f : 0.f);
            for (int cc = 0; cc < 8; ++cc) {
                const int c = ct + cc;
                const float* xc = xn + c * HW_;
                const float val = fmaf(f00, xc[i00], fmaf(f01, xc[i01],
                                  fmaf(f10, xc[i10], f11 * xc[i11])));
#pragma unroll
                for (int o = 0; o < COUT_; ++o)
                    acc[o] = fmaf(wptr[o * (C_ * K_) + c * K_ + k], val, acc[o]);
            }
        }
    }
    float* outp = out + n * (COUT_ * HW_) + hw;
#pragma unroll
    for (int o = 0; o < COUT_; ++o) outp[o * HW_] = acc[o];
}

extern "C" void kernel_launch(void* const* d_in, const int* in_sizes, int n_in,
                              void* d_out, int out_size, void* d_ws, size_t ws_size,
                              hipStream_t stream) {
    const float* x      = (const float*)d_in[0];
    const float* offset = (const float*)d_in[1];
    const float* mask   = (const float*)d_in[2];
    const float* weight = (const float*)d_in[3];
    const float* bias   = (const float*)d_in[4];
    float* out = (float*)d_out;

    const size_t xh_bytes = (size_t)NPIX * C_ * sizeof(float);     // 16.8 MB
    const size_t wA_bytes = (size_t)COUT_ * KK_ * sizeof(u16);     // 73.7 KB

    if (ws_size >= xh_bytes + wA_bytes) {
        float* xh  = (float*)d_ws;
        u16*   wA3 = (u16*)((char*)d_ws + xh_bytes);
        prep<<<1024 + 144, 256, 0, stream>>>(x, xh, weight, wA3);
        dcn_fused<<<NPIX / 64, 256, 0, stream>>>(xh, offset, mask, wA3, bias, out);
    } else {
        dcn_fallback<<<NPIX / 256, 256, 0, stream>>>(x, offset, mask, weight, bias, out);
    }
}

// Round 3
// 109.553 us; speedup vs baseline: 1.6007x; 1.0923x over previous
//
#include <hip/hip_runtime.h>

// DCNv2 forward = prep (weight repack + NHWC fp16 transpose) + FUSED
// im2col+GEMM. R15: fp16 end-to-end gather on the verified R14 skeleton.
//   xh is NHWC fp16 -> gather loads are dwordx4 = 8 channels/lane,
//   eighth-wave per (pixel,corner): 8 loads/tap/wave (was 16), half bytes.
//   Bilinear combine in packed fp16 (v_pk_fma_f16), result IS the MFMA
//   operand dtype -> no cvt, FINISH VALU halved. MFMA 16x16x32_f16.
//   Stages 2 x 32 VGPR (was 2 x 64) -> launch_bounds(256,4): 16 waves/CU,
//   all 4 blocks/CU resident. Pipeline: ISSUE(t+2) -> LA/LB regs,
//   MFMA(t) <- Bt[t&1], FINISH(t+1) -> Bt[t&1^1], ONE barrier/tap.
#define N_    4
#define C_    64
#define H_    128
#define W_    128
#define KW_   3
#define K_    9
#define COUT_ 64
#define HW_   (H_ * W_)     // 16384
#define NPIX  (N_ * HW_)    // 65536
#define KK_   (C_ * K_)     // 576

typedef _Float16 h2 __attribute__((ext_vector_type(2)));
typedef _Float16 h4 __attribute__((ext_vector_type(4)));
typedef _Float16 h8 __attribute__((ext_vector_type(8)));   // 16B, 4 VGPRs
typedef float v4f __attribute__((ext_vector_type(4)));     // MFMA C/D
typedef int   v4i __attribute__((ext_vector_type(4)));

// ---------------------------------------------------------------------------
// prep: one dispatch doing both prologue jobs.
//   blocks 0..1023  : NCHW fp32 -> NHWC fp16 transpose xh[n][hw][c]
//   blocks 1024..1167: wA3[o][k] = fp16(weight[o][c][tap]), k = tap*64+c
// ---------------------------------------------------------------------------
__global__ __launch_bounds__(256) void prep(
    const float* __restrict__ x, _Float16* __restrict__ xh,
    const float* __restrict__ w, _Float16* __restrict__ wA3)
{
    if (blockIdx.x < 1024) {
        const int n   = blockIdx.x >> 8;            // 4 images x 256 hw-tiles
        const int hw0 = (blockIdx.x & 255) * 64;

        __shared__ float tile[64][65];              // [hw][c], pad
        const float* xb = x + n * (C_ * HW_);
#pragma unroll
        for (int i = 0; i < 4; ++i) {
            const int idx = i * 256 + threadIdx.x;  // 0..1023
            const int q   = idx & 15;               // hw quad 0..15
            const int c   = idx >> 4;               // 0..63
            const v4f v = *(const v4f*)&xb[c * HW_ + hw0 + 4 * q];
            tile[4 * q + 0][c] = v.x;
            tile[4 * q + 1][c] = v.y;
            tile[4 * q + 2][c] = v.z;
            tile[4 * q + 3][c] = v.w;
        }
        __syncthreads();
        _Float16* xo = xh + ((size_t)n * HW_ + hw0) * 64;
#pragma unroll
        for (int i = 0; i < 4; ++i) {
            const int idx = i * 256 + threadIdx.x;
            const int c4  = idx & 15;               // c quad 0..15
            const int hr  = idx >> 4;               // 0..63
            h4 v;
            v.x = (_Float16)tile[hr][4 * c4 + 0];
            v.y = (_Float16)tile[hr][4 * c4 + 1];
            v.z = (_Float16)tile[hr][4 * c4 + 2];
            v.w = (_Float16)tile[hr][4 * c4 + 3];
            *(h4*)&xo[hr * 64 + 4 * c4] = v;        // 8B store, coalesced
        }
    } else {
        const int tid = (blockIdx.x - 1024) * 256 + threadIdx.x;  // 0..36863
        if (tid < COUT_ * KK_) {
            const int k   = tid % KK_;              // tap*64 + c
            const int o   = tid / KK_;
            const int c   = k & 63;
            const int tap = k >> 6;
            wA3[tid] = (_Float16)w[o * (C_ * K_) + c * K_ + tap];
        }
    }
}

// ---------------------------------------------------------------------------
// Fused im2col+GEMM. Block = 256 thr / 4 waves, 64 px x 64 cout.
// Gather identity: eighth-wave per pixel-corner — lane (g = lane>>3 pixel,
// l8 = lane&7 channel-octet). Per load instr: 8 pixels x 128B contiguous.
// Lane owns 2 pixels (g, 8+g) of the wave's 16; stage = 2px x 4corners x h8
// = 32 VGPR. FINISH: per pixel 4 packed-fp16 ops on h8 (v_pk_fma_f16 x16).
// ---------------------------------------------------------------------------
__global__ __launch_bounds__(256, 4) void dcn_fused(
    const _Float16* __restrict__ xh,   // (N, HW, C) fp16
    const float* __restrict__ offset,  // (N, 2*K, H, W)
    const float* __restrict__ mask,    // (N, K, H, W)
    const _Float16* __restrict__ wA3,  // (COUT, KK) fp16, k = tap*64+c
    const float* __restrict__ bias,
    float* __restrict__ out)           // (N, Cout, H, W)
{
    const int tid  = threadIdx.x;
    const int lane = tid & 63;
    const int wv   = tid >> 6;
    const int quad = lane >> 4;        // MFMA: k-octet selector
    const int l16  = lane & 15;        // MFMA: row/col lane
    const int g    = lane >> 3;        // gather: pixel-in-8
    const int l8   = lane & 7;         // gather: channel octet

    const int lb  = (blockIdx.x & 7) * 128 + (blockIdx.x >> 3);  // XCD swizzle
    const int pxb = lb * 64;                     // 64 | HW_: one image per block
    const int n   = pxb >> 14;
    const int hwb = pxb & (HW_ - 1);

    __shared__ _Float16 cwh[576][4];             // 4.6 KB fp16 bilinear weights
    __shared__ int      ci[576][4];              // 9.2 KB corner indices
    __shared__ _Float16 Bt[2][64][72];           // 18.4 KB [buf][px][c pad 72]

    // ---- phase 1: all coefs for this block's 64 px x 9 taps ----
#pragma unroll
    for (int r = 0; r < 3; ++r) {
        const int e = tid + 256 * r;
        if (e < 576) {
            const int p  = e / 9;                // magic-mul
            const int t  = e - p * 9;
            const int hw = hwb + p;
            const int ho = hw >> 7;
            const int wo = hw & (W_ - 1);
            const int ky = t / KW_;
            const int kx = t - ky * KW_;

            const float offy = offset[n * (2 * K_ * HW_) + (2 * t + 0) * HW_ + hw];
            const float offx = offset[n * (2 * K_ * HW_) + (2 * t + 1) * HW_ + hw];
            const float mval = mask[n * (K_ * HW_) + t * HW_ + hw];

            const float py = (float)(ho - 1 + ky) + offy;   // stride=1,pad=1,dil=1
            const float qx = (float)(wo - 1 + kx) + offx;
            const float y0f = floorf(py), x0f = floorf(qx);
            const float ly = py - y0f, lx = qx - x0f;
            const int y0 = (int)y0f, x0 = (int)x0f;
            const int y1 = y0 + 1,   x1 = x0 + 1;
            const bool vy0 = (y0 >= 0) & (y0 < H_);
            const bool vy1 = (y1 >= 0) & (y1 < H_);
            const bool vx0 = (x0 >= 0) & (x0 < W_);
            const bool vx1 = (x1 >= 0) & (x1 < W_);
            const int cy0 = min(max(y0, 0), H_ - 1);
            const int cy1 = min(max(y1, 0), H_ - 1);
            const int cx0 = min(max(x0, 0), W_ - 1);
            const int cx1 = min(max(x1, 0), W_ - 1);

            h4 q;
            q.x = (_Float16)((1.f - ly) * (1.f - lx) * mval * ((vy0 && vx0) ? 1.f : 0.f));
            q.y = (_Float16)((1.f - ly) * lx         * mval * ((vy0 && vx1) ? 1.f : 0.f));
            q.z = (_Float16)(ly         * (1.f - lx) * mval * ((vy1 && vx0) ? 1.f : 0.f));
            q.w = (_Float16)(ly         * lx         * mval * ((vy1 && vx1) ? 1.f : 0.f));
            *(h4*)&cwh[e][0] = q;
            int* qi = &ci[e][0];
            qi[0] = cy0 * W_ + cx0;
            qi[1] = cy0 * W_ + cx1;
            qi[2] = cy1 * W_ + cx0;
            qi[3] = cy1 * W_ + cx1;
        }
    }
    __syncthreads();

    // gather base: this lane's channel octet (16B), fp16 units
    const _Float16* xb8 = xh + ((size_t)n * HW_) * 64 + 8 * l8;
    const int pg  = wv * 16 + g;                 // lane's pixel A (local)
    const int pg8 = pg + 8;                      // lane's pixel B (local)

    // wave's MFMA identity: cout half x pixel half
    const int mb   = (wv & 1) * 32;
    const int pxwl = (wv >> 1) * 32;             // local pixel base for MFMA

    v4f acc[2][2];
#pragma unroll
    for (int mh = 0; mh < 2; ++mh)
#pragma unroll
        for (int nh = 0; nh < 2; ++nh)
            acc[mh][nh] = (v4f){0.f, 0.f, 0.f, 0.f};

    // register stages: [pixel 0/1][corner 0..3], h8 each = 32 VGPR/stage
    h8 LA[2][4], LB[2][4];

    // issue tap t's 8 corner loads into stage R
#define ISSUE(t, R)                                                         \
    {                                                                       \
        const v4i oa = *(const v4i*)&ci[pg  * 9 + (t)][0];                  \
        const v4i ob = *(const v4i*)&ci[pg8 * 9 + (t)][0];                  \
        R[0][0] = *(const h8*)(xb8 + (size_t)oa.x * 64);                    \
        R[0][1] = *(const h8*)(xb8 + (size_t)oa.y * 64);                    \
        R[0][2] = *(const h8*)(xb8 + (size_t)oa.z * 64);                    \
        R[0][3] = *(const h8*)(xb8 + (size_t)oa.w * 64);                    \
        R[1][0] = *(const h8*)(xb8 + (size_t)ob.x * 64);                    \
        R[1][1] = *(const h8*)(xb8 + (size_t)ob.y * 64);                    \
        R[1][2] = *(const h8*)(xb8 + (size_t)ob.z * 64);                    \
        R[1][3] = *(const h8*)(xb8 + (size_t)ob.w * 64);                    \
    }

    // consume stage R for tap t: packed-fp16 bilinear + LDS write
#define FINISH(t, R, b)                                                     \
    {                                                                       \
        _Pragma("unroll")                                                   \
        for (int h = 0; h < 2; ++h) {                                       \
            const int p = wv * 16 + h * 8 + g;                              \
            const h4 f = *(const h4*)&cwh[p * 9 + (t)][0];                  \
            const h8 F0 = {f.x, f.x, f.x, f.x, f.x, f.x, f.x, f.x};         \
            const h8 F1 = {f.y, f.y, f.y, f.y, f.y, f.y, f.y, f.y};         \
            const h8 F2 = {f.z, f.z, f.z, f.z, f.z, f.z, f.z, f.z};         \
            const h8 F3 = {f.w, f.w, f.w, f.w, f.w, f.w, f.w, f.w};         \
            h8 rr = F0 * R[h][0];                                           \
            rr = __builtin_elementwise_fma(F1, R[h][1], rr);                \
            rr = __builtin_elementwise_fma(F2, R[h][2], rr);                \
            rr = __builtin_elementwise_fma(F3, R[h][3], rr);                \
            *(h8*)&Bt[b][p][8 * l8] = rr;                                   \
        }                                                                   \
    }

    // ---- prologue: fill the 2-deep pipeline ----
    ISSUE(0, LA)
    ISSUE(1, LB)
    FINISH(0, LA, 0)
    __syncthreads();

    // ---- main loop: 9 taps, 1 barrier each, loads 2 taps ahead ----
#pragma unroll
    for (int t = 0; t < K_; ++t) {
        const int buf = t & 1;
        if ((t & 1) == 0) {
            if (t + 2 < K_) ISSUE(t + 2, LA)
        } else {
            if (t + 2 < K_) ISSUE(t + 2, LB)
        }

        // MFMA(t): A-frags from wA3 (k = t*64 + kc*32 + quad*8), B from Bt[buf]
#pragma unroll
        for (int kc = 0; kc < 2; ++kc) {
            h8 bfr[2];
#pragma unroll
            for (int nh = 0; nh < 2; ++nh)
                bfr[nh] = *(const h8*)&Bt[buf][pxwl + nh * 16 + l16][kc * 32 + quad * 8];
            h8 afr[2];
#pragma unroll
            for (int mh = 0; mh < 2; ++mh)
                afr[mh] = *(const h8*)(wA3 + (size_t)(mb + mh * 16 + l16) * KK_
                                            + t * 64 + kc * 32 + quad * 8);
#pragma unroll
            for (int mh = 0; mh < 2; ++mh)
#pragma unroll
                for (int nh = 0; nh < 2; ++nh)
                    acc[mh][nh] = __builtin_amdgcn_mfma_f32_16x16x32_f16(
                        afr[mh], bfr[nh], acc[mh][nh], 0, 0, 0);
        }

        if ((t & 1) == 0) {
            if (t + 1 < K_) FINISH(t + 1, LB, buf ^ 1)
        } else {
            if (t + 1 < K_) FINISH(t + 1, LA, buf ^ 1)
        }
        __syncthreads();   // MFMA(t) reads done AND FINISH(t+1) writes done
    }
#undef ISSUE
#undef FINISH

    // D layout (R4-verified, dtype-independent): col = l16 (px), row = quad*4+r
    float* outb = out + n * (COUT_ * HW_);
#pragma unroll
    for (int mh = 0; mh < 2; ++mh)
#pragma unroll
        for (int nh = 0; nh < 2; ++nh)
#pragma unroll
            for (int r = 0; r < 4; ++r) {
                const int m = mb + mh * 16 + quad * 4 + r;
                outb[m * HW_ + hwb + pxwl + nh * 16 + l16] = acc[mh][nh][r] + bias[m];
            }
}

// ---------------------------------------------------------------------------
// Fallback (ws too small): R3-style direct fp32 kernel, no ws needed.
// ---------------------------------------------------------------------------
__global__ __launch_bounds__(256) void dcn_fallback(
    const float* __restrict__ x, const float* __restrict__ offset,
    const float* __restrict__ mask, const float* __restrict__ wptr,
    const float* __restrict__ bias, float* __restrict__ out)
{
    const int pix = blockIdx.x * 256 + threadIdx.x;
    const int n = pix >> 14, hw = pix & (HW_ - 1);
    const int ho = hw >> 7,  wo = hw & (W_ - 1);
    float acc[COUT_];
#pragma unroll
    for (int o = 0; o < COUT_; ++o) acc[o] = bias[o];
    const float* xn   = x + n * (C_ * HW_);
    const float* offn = offset + n * (2 * K_ * HW_) + hw;
    const float* mn   = mask + n * (K_ * HW_) + hw;
    for (int ct = 0; ct < C_; ct += 8) {
        for (int k = 0; k < K_; ++k) {
            const int ky = k / KW_, kx = k - ky * KW_;
            const float off_y = offn[(2 * k + 0) * HW_];
            const float off_x = offn[(2 * k + 1) * HW_];
            const float m = mn[k * HW_];
            const float py = (float)(ho - 1 + ky) + off_y;
            const float px = (float)(wo - 1 + kx) + off_x;
            const float y0f = floorf(py), x0f = floorf(px);
            const float ly = py - y0f, lx = px - x0f;
            const int y0 = (int)y0f, x0 = (int)x0f, y1 = y0 + 1, x1 = x0 + 1;
            const bool vy0 = (y0 >= 0) & (y0 < H_), vy1 = (y1 >= 0) & (y1 < H_);
            const bool vx0 = (x0 >= 0) & (x0 < W_), vx1 = (x1 >= 0) & (x1 < W_);
            const int cy0 = min(max(y0, 0), H_ - 1), cy1 = min(max(y1, 0), H_ - 1);
            const int cx0 = min(max(x0, 0), W_ - 1), cx1 = min(max(x1, 0), W_ - 1);
            const int i00 = cy0 * W_ + cx0, i01 = cy0 * W_ + cx1;
            const int i10 = cy1 * W_ + cx0, i11 = cy1 * W_ + cx1;
            const float f00 = (1.f - ly) * (1.f - lx) * m * ((vy0 && vx0) ? 1.f : 0.f);
            const float f01 = (1.f - ly) * lx * m * ((vy0 && vx1) ? 1.f : 0.f);
            const float f10 = ly * (1.f - lx) * m * ((vy1 && vx0) ? 1.f : 0.f);
            const float f11 = ly * lx * m * ((vy1 && vx1) ? 1.f : 0.f);
            for (int cc = 0; cc < 8; ++cc) {
                const int c = ct + cc;
                const float* xc = xn + c * HW_;
                const float val = fmaf(f00, xc[i00], fmaf(f01, xc[i01],
                                  fmaf(f10, xc[i10], f11 * xc[i11])));
#pragma unroll
                for (int o = 0; o < COUT_; ++o)
                    acc[o] = fmaf(wptr[o * (C_ * K_) + c * K_ + k], val, acc[o]);
            }
        }
    }
    float* outp = out + n * (COUT_ * HW_) + hw;
#pragma unroll
    for (int o = 0; o < COUT_; ++o) outp[o * HW_] = acc[o];
}

extern "C" void kernel_launch(void* const* d_in, const int* in_sizes, int n_in,
                              void* d_out, int out_size, void* d_ws, size_t ws_size,
                              hipStream_t stream) {
    const float* x      = (const float*)d_in[0];
    const float* offset = (const float*)d_in[1];
    const float* mask   = (const float*)d_in[2];
    const float* weight = (const float*)d_in[3];
    const float* bias   = (const float*)d_in[4];
    float* out = (float*)d_out;

    const size_t xh_bytes = (size_t)NPIX * C_ * sizeof(_Float16);  // 8.4 MB
    const size_t wA_bytes = (size_t)COUT_ * KK_ * sizeof(_Float16);// 73.7 KB

    if (ws_size >= xh_bytes + wA_bytes) {
        _Float16* xh  = (_Float16*)d_ws;
        _Float16* wA3 = (_Float16*)((char*)d_ws + xh_bytes);
        prep<<<1024 + 144, 256, 0, stream>>>(x, xh, weight, wA3);
        dcn_fused<<<NPIX / 64, 256, 0, stream>>>(xh, offset, mask, wA3, bias, out);
    } else {
        dcn_fallback<<<NPIX / 256, 256, 0, stream>>>(x, offset, mask, weight, bias, out);
    }
}